// Round 2
// baseline (4911.197 us; speedup 1.0000x reference)
//
#include <hip/hip_runtime.h>
#include <hip/hip_bf16.h>
#include <hip/hip_cooperative_groups.h>

namespace cg = cooperative_groups;

#define BB_ 64
#define SS_ 50
#define TT_ 25
#define HH_ 1024
#define VV_ 32000

typedef __bf16 bf16x8 __attribute__((ext_vector_type(8)));
typedef float f32x4 __attribute__((ext_vector_type(4)));

__device__ __forceinline__ unsigned short f2b(float f) {
  unsigned u = __float_as_uint(f);
  u = (u + 0x7FFFu + ((u >> 16) & 1u)) >> 16;  // RNE
  return (unsigned short)u;
}
__device__ __forceinline__ float b2f(unsigned short u) {
  return __uint_as_float((unsigned)u << 16);
}
__device__ __forceinline__ float fast_tanh(float x) {
  float e = __expf(2.f * x);
  return 1.f - 2.f / (e + 1.f);
}
__device__ __forceinline__ float fast_sigmoid(float x) {
  return 1.f / (1.f + __expf(-x));
}
__device__ __forceinline__ void gload16(const void* g, void* l) {
  __builtin_amdgcn_global_load_lds((const __attribute__((address_space(1))) void*)g,
                                   (__attribute__((address_space(3))) void*)l, 16, 0, 0);
}
__device__ __forceinline__ bf16x8 ldb8(const unsigned short* p) {
  return *(const bf16x8*)p;
}

// ---------- converts / gathers ----------
__global__ __launch_bounds__(256) void cvt_bf16(const float* __restrict__ src,
                                                unsigned short* __restrict__ dst, long n) {
  long i = ((long)blockIdx.x * 256 + threadIdx.x) * 4;
  if (i >= n) return;
  float4 v = *(const float4*)(src + i);
  *(ushort4*)(dst + i) = make_ushort4(f2b(v.x), f2b(v.y), f2b(v.z), f2b(v.w));
}

__global__ __launch_bounds__(256) void embed_gather(const int* __restrict__ tgt,
                                                    const float* __restrict__ emb,
                                                    unsigned short* __restrict__ X) {
  long idx = ((long)blockIdx.x * 256 + threadIdx.x) * 4;
  if (idx >= (long)1600 * HH_) return;
  int col = (int)(idx & (HH_ - 1));
  int r = (int)(idx >> 10);          // row = b*25 + t
  int t = r % 25;
  int tok = (t == 0) ? 1 : tgt[r - 1];   // SOS=1; tgt flat [B,T]
  float4 v = *(const float4*)(emb + (long)tok * HH_ + col);
  *(ushort4*)(X + idx) = make_ushort4(f2b(v.x), f2b(v.y), f2b(v.z), f2b(v.w));
}

__global__ __launch_bounds__(256) void init_h(const float* __restrict__ eh,
                                              float* __restrict__ Hf,
                                              unsigned short* __restrict__ Hb) {
  int i = (blockIdx.x * 256 + threadIdx.x) * 4;
  if (i >= BB_ * HH_) return;
  float4 v = *(const float4*)(eh + i);
  *(float4*)(Hf + i) = v;
  *(ushort4*)(Hb + i) = make_ushort4(f2b(v.x), f2b(v.y), f2b(v.z), f2b(v.w));
}

// ---------- big GEMM: out[M x ldo] = A[Mpad x 1024](bf16) @ W[N x ldw]^T + bias ----------
// m97 structure + XOR bank swizzle: stage src chunk (scg^x(row)) at slot scg; read slot q^x(row).
__global__ __launch_bounds__(256) void gemm128_bt(
    const unsigned short* __restrict__ A, const unsigned short* __restrict__ W,
    const float* __restrict__ bias, float* __restrict__ out, long ldo,
    int Mtiles, int ldw, int Mvalid) {
  __shared__ __align__(16) unsigned short As[128 * 32];
  __shared__ __align__(16) unsigned short Bs[128 * 32];
  int bid = blockIdx.x;
  int m0 = (bid % Mtiles) * 128;
  int n0 = (bid / Mtiles) * 128;
  int tid = threadIdx.x;
  int w = tid >> 6, l = tid & 63;
  int srow = tid >> 2, scg = tid & 3;
  int xr = (srow >> 1) & 3;                 // bank swizzle key
  int mw = (w & 1) * 64, nw = (w >> 1) * 64;
  int lc = l & 15, lq = l >> 4;

  const unsigned short* Ag0 = A + (long)(m0 + srow) * 1024 + (scg ^ xr) * 8;
  const unsigned short* Ag1 = Ag0 + 64 * 1024;
  const unsigned short* Wg0 = W + (long)(n0 + srow) * ldw + (scg ^ xr) * 8;
  const unsigned short* Wg1 = Wg0 + (long)64 * ldw;
  unsigned short* lA0 = As + tid * 8;
  unsigned short* lA1 = As + 2048 + tid * 8;
  unsigned short* lB0 = Bs + tid * 8;
  unsigned short* lB1 = Bs + 2048 + tid * 8;

  f32x4 zero = {0.f, 0.f, 0.f, 0.f};
  f32x4 acc[4][4];
#pragma unroll
  for (int i = 0; i < 4; ++i)
#pragma unroll
    for (int j = 0; j < 4; ++j) acc[i][j] = zero;

  for (int k0 = 0; k0 < 1024; k0 += 32) {
    __syncthreads();
    gload16(Ag0 + k0, lA0);
    gload16(Ag1 + k0, lA1);
    gload16(Wg0 + k0, lB0);
    gload16(Wg1 + k0, lB1);
    __syncthreads();
    bf16x8 af[4], bg[4];
#pragma unroll
    for (int mt = 0; mt < 4; ++mt) {
      int r = mw + mt * 16 + lc;
      af[mt] = ldb8(As + r * 32 + ((lq ^ ((r >> 1) & 3)) * 8));
    }
#pragma unroll
    for (int nt = 0; nt < 4; ++nt) {
      int r = nw + nt * 16 + lc;
      bg[nt] = ldb8(Bs + r * 32 + ((lq ^ ((r >> 1) & 3)) * 8));
    }
#pragma unroll
    for (int mt = 0; mt < 4; ++mt)
#pragma unroll
      for (int nt = 0; nt < 4; ++nt)
        acc[mt][nt] = __builtin_amdgcn_mfma_f32_16x16x32_bf16(af[mt], bg[nt], acc[mt][nt], 0, 0, 0);
  }

  int lr = lq * 4;
#pragma unroll
  for (int nt = 0; nt < 4; ++nt) {
    int col = n0 + nw + nt * 16 + lc;
    float bv = bias[col];
#pragma unroll
    for (int mt = 0; mt < 4; ++mt) {
#pragma unroll
      for (int r = 0; r < 4; ++r) {
        int m = m0 + mw + mt * 16 + lr + r;
        if (m < Mvalid) out[(long)m * ldo + col] = acc[mt][nt][r] + bv;
      }
    }
  }
}

// ---------- persistent cooperative recurrence: all 25 steps, 3 grid syncs/step ----------
// grid 256 blocks x 256 thr (1 block/CU). Sticky tile->CU mapping => weights L2-resident.
__global__ __launch_bounds__(256, 1) void rnn_steps(
    float* __restrict__ Hf, unsigned short* __restrict__ Hb,
    const unsigned short* __restrict__ WAB, const unsigned short* __restrict__ WHHB,
    const unsigned short* __restrict__ WIHB,
    const float* __restrict__ ba, const float* __restrict__ bhh,
    const unsigned short* __restrict__ KEYSB, const float* __restrict__ Va,
    const unsigned short* __restrict__ ENCB, const float* __restrict__ GA,
    float* __restrict__ Qf, float* __restrict__ GHf,
    unsigned short* __restrict__ CTXB, unsigned short* __restrict__ HALLB) {
  cg::grid_group grid = cg::this_grid();
  int gid = blockIdx.x;
  int tid = threadIdx.x;
  int w = tid >> 6, l = tid & 63;
  int lc = l & 15, lq = l >> 4, lr = (l >> 4) * 4;
  __shared__ float sc[64];
  __shared__ float wgt[64];

  // P1 loop-invariant setup: wave-tile nt = gid (0..255 over [q|gh] cols), mt = w
  const unsigned short* Wp1;
  const float* bp1;
  float* op1;
  long ldo1;
  {
    int n = gid * 16;
    if (n < 1024) { Wp1 = WAB + (long)n * 1024; bp1 = ba + n; op1 = Qf + n; ldo1 = 1024; }
    else { int n2 = n - 1024; Wp1 = WHHB + (long)n2 * 1024; bp1 = bhh + n2; op1 = GHf + n2; ldo1 = 3072; }
  }
  const unsigned short* Ap1 = Hb + (long)(w * 16 + lc) * 1024 + lq * 8;
  const unsigned short* Bp1 = Wp1 + (long)lc * 1024 + lq * 8;
  float bv1 = bp1[lc];

  // P3 loop-invariant setup (blocks 0..63): mt = w, n-tile = gid
  const unsigned short* Ap3 = CTXB + (long)(w * 16 + lc) * 1024 + lq * 8;
  const unsigned short* B30 = WIHB + (long)(gid * 16 + lc) * 2048 + 1024 + lq * 8;
  const unsigned short* B31 = B30 + (long)1024 * 2048;
  const unsigned short* B32 = B30 + (long)2048 * 2048;

  for (int t = 0; t < TT_; ++t) {
    // ---- P1: q = h@Wa^T+ba ; gh = h@W_hh^T+b_hh ----
    {
      f32x4 acc = {0.f, 0.f, 0.f, 0.f};
#pragma unroll 4
      for (int k = 0; k < 1024; k += 32)
        acc = __builtin_amdgcn_mfma_f32_16x16x32_bf16(ldb8(Ap1 + k), ldb8(Bp1 + k), acc, 0, 0, 0);
#pragma unroll
      for (int r = 0; r < 4; ++r) op1[(long)(w * 16 + lr + r) * ldo1 + lc] = acc[r] + bv1;
    }
    grid.sync();

    // ---- P2: attention for batch b = gid (blocks 0..63) ----
    if (gid < 64) {
      int b = gid;
      const float* q = Qf + (long)b * HH_;
      const unsigned short* kb = KEYSB + (long)b * SS_ * HH_;
      for (int s = w; s < SS_; s += 4) {
        const unsigned short* kr = kb + (long)s * HH_;
        float p = 0.f;
#pragma unroll
        for (int j = 0; j < 16; ++j) {
          int hh = l + j * 64;
          p += fast_tanh(q[hh] + b2f(kr[hh])) * Va[hh];
        }
#pragma unroll
        for (int off = 32; off; off >>= 1) p += __shfl_down(p, off);
        if (l == 0) sc[s] = p;
      }
      __syncthreads();
      if (tid < 64) {
        float v = (tid < SS_) ? sc[tid] : -1e30f;
        float m = v;
#pragma unroll
        for (int off = 32; off; off >>= 1) m = fmaxf(m, __shfl_down(m, off));
        m = __shfl(m, 0);
        float e = (tid < SS_) ? __expf(v - m) : 0.f;
        float ssum = e;
#pragma unroll
        for (int off = 32; off; off >>= 1) ssum += __shfl_down(ssum, off);
        ssum = __shfl(ssum, 0);
        if (tid < SS_) wgt[tid] = e / ssum;
      }
      __syncthreads();
      {
        int c0 = tid * 4;
        const unsigned short* eb = ENCB + (long)b * SS_ * HH_ + c0;
        float a0 = 0.f, a1 = 0.f, a2 = 0.f, a3 = 0.f;
#pragma unroll 10
        for (int s = 0; s < SS_; ++s) {
          ushort4 e = *(const ushort4*)(eb + (long)s * HH_);
          float ww = wgt[s];
          a0 += ww * b2f(e.x); a1 += ww * b2f(e.y);
          a2 += ww * b2f(e.z); a3 += ww * b2f(e.w);
        }
        *(ushort4*)(CTXB + (long)b * HH_ + c0) =
            make_ushort4(f2b(a0), f2b(a1), f2b(a2), f2b(a3));
      }
    }
    grid.sync();

    // ---- P3: ctx-gate GEMM + GRU fusion (blocks 0..63) ----
    if (gid < 64) {
      f32x4 ar = {0.f, 0.f, 0.f, 0.f}, az = ar, an = ar;
#pragma unroll 4
      for (int k = 0; k < 1024; k += 32) {
        bf16x8 a = ldb8(Ap3 + k);
        ar = __builtin_amdgcn_mfma_f32_16x16x32_bf16(a, ldb8(B30 + k), ar, 0, 0, 0);
        az = __builtin_amdgcn_mfma_f32_16x16x32_bf16(a, ldb8(B31 + k), az, 0, 0, 0);
        an = __builtin_amdgcn_mfma_f32_16x16x32_bf16(a, ldb8(B32 + k), an, 0, 0, 0);
      }
      int i = gid * 16 + lc;
#pragma unroll
      for (int r = 0; r < 4; ++r) {
        int bb = w * 16 + lr + r;
        long rowBT = (long)bb * 25 + t;
        const float* ga = GA + rowBT * 3072;
        const float* gh = GHf + (long)bb * 3072;
        float rr = fast_sigmoid(ga[i] + ar[r] + gh[i]);
        float zz = fast_sigmoid(ga[1024 + i] + az[r] + gh[1024 + i]);
        float nn = fast_tanh(ga[2048 + i] + an[r] + rr * gh[2048 + i]);
        float hold = Hf[(long)bb * 1024 + i];
        float hnew = (1.f - zz) * nn + zz * hold;
        Hf[(long)bb * 1024 + i] = hnew;
        unsigned short hb = f2b(hnew);
        Hb[(long)bb * 1024 + i] = hb;
        HALLB[rowBT * 1024 + i] = hb;
      }
    }
    grid.sync();
  }
}

extern "C" void kernel_launch(void* const* d_in, const int* in_sizes, int n_in,
                              void* d_out, int out_size, void* d_ws, size_t ws_size,
                              hipStream_t stream) {
  (void)in_sizes; (void)n_in; (void)out_size; (void)ws_size;
  const float* enc  = (const float*)d_in[0];
  const float* ehid = (const float*)d_in[1];
  const int*   tgt  = (const int*)d_in[2];
  const float* emb  = (const float*)d_in[3];
  const float* Wa   = (const float*)d_in[4];
  const float* ba   = (const float*)d_in[5];
  const float* Ua   = (const float*)d_in[6];
  const float* bu   = (const float*)d_in[7];
  const float* Va   = (const float*)d_in[8];
  const float* Wih  = (const float*)d_in[10];
  const float* bih  = (const float*)d_in[11];
  const float* Whh  = (const float*)d_in[12];
  const float* bhh  = (const float*)d_in[13];
  const float* Wout = (const float*)d_in[14];
  const float* bout = (const float*)d_in[15];
  float* out = (float*)d_out;

  char* p = (char*)d_ws;
  auto alloc = [&](size_t bytes) { char* r = p; p += (bytes + 255) & ~(size_t)255; return r; };
  unsigned short* WOUTB = (unsigned short*)alloc((size_t)VV_ * HH_ * 2);
  unsigned short* WIHB  = (unsigned short*)alloc((size_t)3072 * 2048 * 2);
  unsigned short* WHHB  = (unsigned short*)alloc((size_t)3072 * 1024 * 2);
  unsigned short* WAB   = (unsigned short*)alloc((size_t)1024 * 1024 * 2);
  unsigned short* UAB   = (unsigned short*)alloc((size_t)1024 * 1024 * 2);
  unsigned short* ENCB  = (unsigned short*)alloc((size_t)BB_ * SS_ * HH_ * 2);
  unsigned short* XEMB  = (unsigned short*)alloc((size_t)1664 * HH_ * 2);  // pad 1600->1664
  unsigned short* HALLB = (unsigned short*)alloc((size_t)1664 * HH_ * 2);
  float* KEYS = (float*)alloc((size_t)BB_ * SS_ * HH_ * 4);
  unsigned short* KEYSB = (unsigned short*)alloc((size_t)BB_ * SS_ * HH_ * 2);
  float* GA   = (float*)alloc((size_t)1600 * 3072 * 4);
  float* GHf  = (float*)alloc((size_t)BB_ * 3072 * 4);
  float* Qf   = (float*)alloc((size_t)BB_ * HH_ * 4);
  float* Hf   = (float*)alloc((size_t)BB_ * HH_ * 4);
  unsigned short* Hb = (unsigned short*)alloc((size_t)BB_ * HH_ * 2);
  unsigned short* CTXB = (unsigned short*)alloc((size_t)BB_ * HH_ * 2);

  auto cvt = [&](const float* s, unsigned short* d, long n) {
    cvt_bf16<<<dim3((unsigned)((n / 4 + 255) / 256)), dim3(256), 0, stream>>>(s, d, n);
  };
  cvt(Wout, WOUTB, (long)VV_ * HH_);
  cvt(Wih, WIHB, (long)3072 * 2048);
  cvt(Whh, WHHB, (long)3072 * 1024);
  cvt(Wa, WAB, (long)1024 * 1024);
  cvt(Ua, UAB, (long)1024 * 1024);
  cvt(enc, ENCB, (long)BB_ * SS_ * HH_);
  embed_gather<<<dim3(1600 * HH_ / 4 / 256), dim3(256), 0, stream>>>(tgt, emb, XEMB);
  init_h<<<dim3(BB_ * HH_ / 4 / 256), dim3(256), 0, stream>>>(ehid, Hf, Hb);

  // keys_proj = enc @ Ua^T + bu : [3200,1024], then bf16 copy for the step kernel
  gemm128_bt<<<dim3(25 * 8), dim3(256), 0, stream>>>(ENCB, UAB, bu, KEYS, (long)1024, 25, 1024, 3200);
  cvt(KEYS, KEYSB, (long)BB_ * SS_ * HH_);
  // gA = Xemb @ W_ih[:, :H]^T + b_ih : [1600,3072]
  gemm128_bt<<<dim3(13 * 24), dim3(256), 0, stream>>>(XEMB, WIHB, bih, GA, (long)3072, 13, 2048, 1600);

  // whole recurrence: one cooperative kernel
  {
    void* kargs[] = {&Hf, &Hb, &WAB, &WHHB, &WIHB, &ba, &bhh, &KEYSB, &Va,
                     &ENCB, &GA, &Qf, &GHf, &CTXB, &HALLB};
    hipLaunchCooperativeKernel((const void*)rnn_steps, dim3(256), dim3(256), kargs, 0, stream);
  }

  // logits = Hall @ Wout^T + bout, rows (b*25+t) -> out[B,T,V] directly
  gemm128_bt<<<dim3(13 * 250), dim3(256), 0, stream>>>(HALLB, WOUTB, bout, out, (long)VV_, 13, 1024, 1600);
}